// Round 5
// baseline (112.110 us; speedup 1.0000x reference)
//
#include <hip/hip_runtime.h>
#include <math.h>

#define DIM 4096
#define NRF 8192
#define NBLK 1024
#define TPB  512
#define NV4  (DIM / 4)        // 1024 float4 per row
#define ROWS_PER_BLOCK 8      // 8 waves/block, 1 row per wave

typedef float f32x4 __attribute__((ext_vector_type(4)));

// Single fused dispatch (plus a 4-byte async memset of the arrival counter).
// grid = 1024 x 512 (8 waves). Wave w of block b owns rf row = b*8+w:
// dot(gs_x[row],x) + dot(gs_w[row],w), x/w staged in LDS, sumsq fused.
//
// Cross-block reduction: every block stores its f32 partial, release-fences,
// then ACQ_REL agent-scope fetch_add on the counter. The counter is memset to
// 0 on the stream before each launch, so the block seeing old+1 == NBLK is
// genuinely the last arrival: all 1024 partials are stored AND release-fenced
// before its increment. It acquire-fences and reduces in f64 (fixed order).
// R4 lesson: (old+1) % NBLK == 0 with an unknown initial counter value picks
// an EARLY arrival (0xAA poison ≡ 682 mod 1024) — counter must start at 0.
__global__ __launch_bounds__(TPB, 4) void k_main(const f32x4* __restrict__ gsx,
                                                 const f32x4* __restrict__ gsw,
                                                 const float* __restrict__ xis,
                                                 const f32x4* __restrict__ x4,
                                                 const f32x4* __restrict__ w4,
                                                 float* __restrict__ partials,
                                                 unsigned int* counter,
                                                 float* __restrict__ out) {
    __shared__ f32x4 lx[NV4];
    __shared__ f32x4 lw[NV4];
    __shared__ float ssq_s[8];
    __shared__ float wsum[8];
    __shared__ int   is_last;

    int t = threadIdx.x;
    int lane = t & 63;
    int wid  = t >> 6;

    // Stage x, w into LDS (each thread moves 2 vec4 of each).
    f32x4 a0 = x4[t], a1 = x4[t + TPB];
    f32x4 b0 = w4[t], b1 = w4[t + TPB];
    lx[t] = a0; lx[t + TPB] = a1;
    lw[t] = b0; lw[t + TPB] = b1;

    // Fused ||x||^2 + ||w||^2 from staged registers.
    float ssq = a0.x*a0.x + a0.y*a0.y + a0.z*a0.z + a0.w*a0.w
              + a1.x*a1.x + a1.y*a1.y + a1.z*a1.z + a1.w*a1.w
              + b0.x*b0.x + b0.y*b0.y + b0.z*b0.z + b0.w*b0.w
              + b1.x*b1.x + b1.y*b1.y + b1.z*b1.z + b1.w*b1.w;
    #pragma unroll
    for (int off = 32; off >= 1; off >>= 1) ssq += __shfl_xor(ssq, off);
    if (lane == 0) ssq_s[wid] = ssq;
    __syncthreads();
    float sxw = ssq_s[0] + ssq_s[1] + ssq_s[2] + ssq_s[3]
              + ssq_s[4] + ssq_s[5] + ssq_s[6] + ssq_s[7];

    int row = blockIdx.x * ROWS_PER_BLOCK + wid;
    const f32x4* __restrict__ rx = gsx + (size_t)row * NV4;
    const f32x4* __restrict__ rw = gsw + (size_t)row * NV4;

    float dx0 = 0.f, dx1 = 0.f, dw0 = 0.f, dw1 = 0.f;
    #pragma unroll
    for (int k = 0; k < NV4 / 64; k += 2) {        // 8 unrolled iters, 2-way ILP
        f32x4 a = rx[k * 64 + lane];
        f32x4 b = lx[k * 64 + lane];
        dx0 += a.x*b.x + a.y*b.y + a.z*b.z + a.w*b.w;
        f32x4 c = rx[(k + 1) * 64 + lane];
        f32x4 d = lx[(k + 1) * 64 + lane];
        dx1 += c.x*d.x + c.y*d.y + c.z*d.z + c.w*d.w;
        f32x4 e = rw[k * 64 + lane];
        f32x4 f = lw[k * 64 + lane];
        dw0 += e.x*f.x + e.y*f.y + e.z*f.z + e.w*f.w;
        f32x4 g = rw[(k + 1) * 64 + lane];
        f32x4 h = lw[(k + 1) * 64 + lane];
        dw1 += g.x*h.x + g.y*h.y + g.z*h.z + g.w*h.w;
    }
    float s = (dx0 + dx1) + (dw0 + dw1);
    #pragma unroll
    for (int off = 32; off >= 1; off >>= 1) s += __shfl_xor(s, off);

    if (lane == 0) {
        float xi = xis[row];
        float e  = xi * s - 0.5f * xi * xi * sxw;
        wsum[wid] = expf(e);
    }
    __syncthreads();
    if (t == 0) {
        float bsum = wsum[0] + wsum[1] + wsum[2] + wsum[3]
                   + wsum[4] + wsum[5] + wsum[6] + wsum[7];
        partials[blockIdx.x] = bsum;
        __threadfence();                               // release: partial visible device-wide
        unsigned int old = __hip_atomic_fetch_add(counter, 1u,
                                                  __ATOMIC_ACQ_REL,
                                                  __HIP_MEMORY_SCOPE_AGENT);
        is_last = (old + 1u == (unsigned)NBLK) ? 1 : 0;
    }
    __syncthreads();

    if (is_last) {
        __threadfence();                               // acquire: see all partials
        double a = 0.0;
        for (int i = t; i < NBLK; i += TPB) a += (double)partials[i];
        #pragma unroll
        for (int off = 32; off >= 1; off >>= 1) a += __shfl_xor(a, off);
        __shared__ double sred[8];
        if (lane == 0) sred[wid] = a;
        __syncthreads();
        if (t == 0) {
            double tot = sred[0] + sred[1] + sred[2] + sred[3]
                       + sred[4] + sred[5] + sred[6] + sred[7];
            out[0] = (float)(tot * (1.0 / (double)NRF));
        }
    }
}

extern "C" void kernel_launch(void* const* d_in, const int* in_sizes, int n_in,
                              void* d_out, int out_size, void* d_ws, size_t ws_size,
                              hipStream_t stream) {
    const float* x    = (const float*)d_in[0];   // [4096]
    const float* w    = (const float*)d_in[1];   // [4096]
    const float* xis  = (const float*)d_in[2];   // [8192]
    const f32x4* gsx  = (const f32x4*)d_in[3];   // [8192,4096]
    const f32x4* gsw  = (const f32x4*)d_in[4];   // [8192,4096]
    float* out = (float*)d_out;

    float* partials       = (float*)d_ws;                       // [NBLK]
    unsigned int* counter = (unsigned int*)((char*)d_ws + 4096);

    hipMemsetAsync(counter, 0, sizeof(unsigned int), stream);   // counter MUST start at 0
    k_main<<<NBLK, TPB, 0, stream>>>(gsx, gsw, xis,
                                     (const f32x4*)x, (const f32x4*)w,
                                     partials, counter, out);
}

// Round 6
// 50.316 us; speedup vs baseline: 2.2281x; 2.2281x over previous
//
#include <hip/hip_runtime.h>
#include <math.h>

#define DIM 4096
#define NRF 8192
#define NBLK 1024
#define TPB  512
#define NV4  (DIM / 4)        // 1024 float4 per row
#define ROWS_PER_BLOCK 8      // 8 waves/block, 1 row per wave

typedef float f32x4 __attribute__((ext_vector_type(4)));

// Single fused dispatch + 4-byte memset of d_out.
// grid = 1024 x 512 (8 waves). Wave w of block b owns rf row = b*8+w:
// dot(gs_x[row],x) + dot(gs_w[row],w), x/w staged in LDS, sumsq fused.
//
// Reduction: ONE relaxed device-scope float atomicAdd per block onto the
// memset-zeroed d_out. No fences, no arrival counter, no last-block reduce —
// R5 showed the ACQ_REL fence pattern (buffer_wbl2/buffer_inv on non-coherent
// L2s) halves delivered BW chip-wide; plain atomicAdd emits no cache
// maintenance. Order variation across replays perturbs the sum by ~1e-9,
// far below the 2.4e-4 threshold.
__global__ __launch_bounds__(TPB, 4) void k_main(const f32x4* __restrict__ gsx,
                                                 const f32x4* __restrict__ gsw,
                                                 const float* __restrict__ xis,
                                                 const f32x4* __restrict__ x4,
                                                 const f32x4* __restrict__ w4,
                                                 float* __restrict__ out) {
    __shared__ f32x4 lx[NV4];
    __shared__ f32x4 lw[NV4];
    __shared__ float ssq_s[8];
    __shared__ float wsum[8];

    int t = threadIdx.x;
    int lane = t & 63;
    int wid  = t >> 6;

    // Stage x, w into LDS (each thread moves 2 vec4 of each).
    f32x4 a0 = x4[t], a1 = x4[t + TPB];
    f32x4 b0 = w4[t], b1 = w4[t + TPB];
    lx[t] = a0; lx[t + TPB] = a1;
    lw[t] = b0; lw[t + TPB] = b1;

    // Fused ||x||^2 + ||w||^2 from staged registers.
    float ssq = a0.x*a0.x + a0.y*a0.y + a0.z*a0.z + a0.w*a0.w
              + a1.x*a1.x + a1.y*a1.y + a1.z*a1.z + a1.w*a1.w
              + b0.x*b0.x + b0.y*b0.y + b0.z*b0.z + b0.w*b0.w
              + b1.x*b1.x + b1.y*b1.y + b1.z*b1.z + b1.w*b1.w;
    #pragma unroll
    for (int off = 32; off >= 1; off >>= 1) ssq += __shfl_xor(ssq, off);
    if (lane == 0) ssq_s[wid] = ssq;
    __syncthreads();
    float sxw = ssq_s[0] + ssq_s[1] + ssq_s[2] + ssq_s[3]
              + ssq_s[4] + ssq_s[5] + ssq_s[6] + ssq_s[7];

    int row = blockIdx.x * ROWS_PER_BLOCK + wid;
    const f32x4* __restrict__ rx = gsx + (size_t)row * NV4;
    const f32x4* __restrict__ rw = gsw + (size_t)row * NV4;

    float dx0 = 0.f, dx1 = 0.f, dw0 = 0.f, dw1 = 0.f;
    #pragma unroll
    for (int k = 0; k < NV4 / 64; k += 2) {        // 8 unrolled iters, 2-way ILP
        f32x4 a = rx[k * 64 + lane];
        f32x4 b = lx[k * 64 + lane];
        dx0 += a.x*b.x + a.y*b.y + a.z*b.z + a.w*b.w;
        f32x4 c = rx[(k + 1) * 64 + lane];
        f32x4 d = lx[(k + 1) * 64 + lane];
        dx1 += c.x*d.x + c.y*d.y + c.z*d.z + c.w*d.w;
        f32x4 e = rw[k * 64 + lane];
        f32x4 f = lw[k * 64 + lane];
        dw0 += e.x*f.x + e.y*f.y + e.z*f.z + e.w*f.w;
        f32x4 g = rw[(k + 1) * 64 + lane];
        f32x4 h = lw[(k + 1) * 64 + lane];
        dw1 += g.x*h.x + g.y*h.y + g.z*h.z + g.w*h.w;
    }
    float s = (dx0 + dx1) + (dw0 + dw1);
    #pragma unroll
    for (int off = 32; off >= 1; off >>= 1) s += __shfl_xor(s, off);

    if (lane == 0) {
        float xi = xis[row];
        float e  = xi * s - 0.5f * xi * xi * sxw;
        wsum[wid] = expf(e);
    }
    __syncthreads();
    if (t == 0) {
        float bsum = (wsum[0] + wsum[1] + wsum[2] + wsum[3]
                    + wsum[4] + wsum[5] + wsum[6] + wsum[7]) * (1.0f / (float)NRF);
        atomicAdd(out, bsum);   // relaxed device-scope, no cache-maintenance ops
    }
}

extern "C" void kernel_launch(void* const* d_in, const int* in_sizes, int n_in,
                              void* d_out, int out_size, void* d_ws, size_t ws_size,
                              hipStream_t stream) {
    const float* x    = (const float*)d_in[0];   // [4096]
    const float* w    = (const float*)d_in[1];   // [4096]
    const float* xis  = (const float*)d_in[2];   // [8192]
    const f32x4* gsx  = (const f32x4*)d_in[3];   // [8192,4096]
    const f32x4* gsw  = (const f32x4*)d_in[4];   // [8192,4096]
    float* out = (float*)d_out;

    hipMemsetAsync(out, 0, sizeof(float), stream);
    k_main<<<NBLK, TPB, 0, stream>>>(gsx, gsw, xis,
                                     (const f32x4*)x, (const f32x4*)w, out);
}